// Round 1
// baseline (4045.781 us; speedup 1.0000x reference)
//
#include <hip/hip_runtime.h>
#include <hip/hip_bf16.h>
#include <cstdint>

#define DEVINL __device__ __forceinline__

// ---------------------------------------------------------------------------
// Problem: 2-layer GCN (with gcn_norm self-loops) -> per-pair MLP -> per-graph
// segment softmax. All fp32 (threshold is 2% of max output; fp32 is safe).
// N=100000, F_IN=64, E=ES=1e6, G=128 (num_graphs fixed by problem setup).
// ---------------------------------------------------------------------------

// ---------- degree / norm ----------
__global__ void k_deg_init(float* deg, int N) {
  int i = blockIdx.x * 256 + threadIdx.x;
  if (i < N) deg[i] = 1.0f;  // self-loop weight (fill_value=1)
}
__global__ void k_deg_acc(const int* __restrict__ col, const float* __restrict__ w,
                          float* deg, int E) {
  int e = blockIdx.x * 256 + threadIdx.x;
  if (e < E) atomicAdd(&deg[col[e]], w[e]);
}
__global__ void k_deg_inv(float* deg, int N) {
  int i = blockIdx.x * 256 + threadIdx.x;
  if (i < N) { float d = deg[i]; deg[i] = d > 0.f ? 1.0f / sqrtf(d) : 0.f; }
}
__global__ void k_norm(const int* __restrict__ row, const int* __restrict__ col,
                       const float* __restrict__ w, const float* __restrict__ dinv,
                       float* __restrict__ normE, int E) {
  int e = blockIdx.x * 256 + threadIdx.x;
  if (e < E) normE[e] = dinv[row[e]] * w[e] * dinv[col[e]];
}

// ---------- tiled fp32 GEMM: C[N,M] = A[N,K] @ W[K,M] (+bias) ----------
// 128-row x M-col block tile, 256 threads, microtile 8 rows x 4*NB cols.
// Rows strided (rg + 16*ri) so the per-instr LDS row reads hit distinct banks.
template<int K, int M, bool BIAS>
__global__ __launch_bounds__(256, 2) void k_gemm(const float* __restrict__ A,
                                                 const float* __restrict__ W,
                                                 const float* __restrict__ bias,
                                                 float* __restrict__ C, int N) {
  constexpr int KC = 64;
  constexpr int NB = M / 64;
  __shared__ alignas(16) float sA[128 * 68];       // [r][k], stride 68
  __shared__ alignas(16) float sW[KC * (M + 4)];   // [k][c], stride M+4
  const int t = threadIdx.x;
  const int rg = t >> 4, cg = t & 15;
  const int r0 = blockIdx.x * 128;
  float acc[NB][8][4] = {};
  for (int kc = 0; kc < K; kc += KC) {
    __syncthreads();
#pragma unroll
    for (int i = 0; i < 8; i++) {           // stage A: 128x64 floats
      int idx = t * 4 + i * 1024;
      int r = idx >> 6, k = idx & 63;
      int gr = r0 + r;
      float4 v = make_float4(0.f, 0.f, 0.f, 0.f);
      if (gr < N) v = *(const float4*)&A[(size_t)gr * K + kc + k];
      *(float4*)&sA[r * 68 + k] = v;
    }
#pragma unroll
    for (int i = 0; i < KC * M / 1024; i++) {  // stage W chunk
      int idx = t * 4 + i * 1024;
      int r = idx / M, c = idx % M;
      *(float4*)&sW[r * (M + 4) + c] = *(const float4*)&W[(size_t)(kc + r) * M + c];
    }
    __syncthreads();
#pragma unroll
    for (int k0 = 0; k0 < KC; k0 += 4) {
      float4 av[8];
#pragma unroll
      for (int ri = 0; ri < 8; ri++) av[ri] = *(const float4*)&sA[(rg + 16 * ri) * 68 + k0];
      float4 wv[4][NB];
#pragma unroll
      for (int kk = 0; kk < 4; kk++)
#pragma unroll
        for (int b = 0; b < NB; b++)
          wv[kk][b] = *(const float4*)&sW[(k0 + kk) * (M + 4) + b * 64 + cg * 4];
#pragma unroll
      for (int kk = 0; kk < 4; kk++)
#pragma unroll
        for (int ri = 0; ri < 8; ri++) {
          float a = ((const float*)&av[ri])[kk];
#pragma unroll
          for (int b = 0; b < NB; b++) {
            acc[b][ri][0] = fmaf(a, wv[kk][b].x, acc[b][ri][0]);
            acc[b][ri][1] = fmaf(a, wv[kk][b].y, acc[b][ri][1]);
            acc[b][ri][2] = fmaf(a, wv[kk][b].z, acc[b][ri][2]);
            acc[b][ri][3] = fmaf(a, wv[kk][b].w, acc[b][ri][3]);
          }
        }
    }
  }
#pragma unroll
  for (int ri = 0; ri < 8; ri++) {
    int rrow = r0 + rg + 16 * ri;
    if (rrow < N) {
#pragma unroll
      for (int b = 0; b < NB; b++) {
        float4 o;
        o.x = acc[b][ri][0]; o.y = acc[b][ri][1]; o.z = acc[b][ri][2]; o.w = acc[b][ri][3];
        if (BIAS) {
          float4 bv = *(const float4*)&bias[b * 64 + cg * 4];
          o.x += bv.x; o.y += bv.y; o.z += bv.z; o.w += bv.w;
        }
        *(float4*)&C[(size_t)rrow * M + b * 64 + cg * 4] = o;
      }
    }
  }
}

// ---------- edge scatter-aggregate: agg[col] += hw[row] * norm ----------
template<int M>
__global__ void k_scatter(const int* __restrict__ row, const int* __restrict__ col,
                          const float* __restrict__ normE, const float* __restrict__ hw,
                          float* __restrict__ agg, int E) {
  constexpr int TPE = M / 4;
  int gid = blockIdx.x * 256 + threadIdx.x;
  int e = gid / TPE;
  if (e >= E) return;
  int j = (gid % TPE) * 4;
  float n = normE[e];
  float4 v = *(const float4*)&hw[(size_t)row[e] * M + j];
  float* dst = &agg[(size_t)col[e] * M + j];
  atomicAdd(dst + 0, v.x * n);
  atomicAdd(dst + 1, v.y * n);
  atomicAdd(dst + 2, v.z * n);
  atomicAdd(dst + 3, v.w * n);
}

// h = (agg + hw*dinv^2 + b), optional relu; in-place over agg
template<int M, bool RELU>
__global__ void k_finalize(float* __restrict__ agg, const float* __restrict__ hw,
                           const float* __restrict__ dinv, const float* __restrict__ bias,
                           int N) {
  constexpr int TPN = M / 4;
  int gid = blockIdx.x * 256 + threadIdx.x;
  int i = gid / TPN;
  if (i >= N) return;
  int j = (gid % TPN) * 4;
  float d = dinv[i];
  float s = d * d;
  float4 a = *(const float4*)&agg[(size_t)i * M + j];
  float4 h = *(const float4*)&hw[(size_t)i * M + j];
  float4 b = *(const float4*)&bias[j];
  float4 o;
  o.x = fmaf(h.x, s, a.x) + b.x;
  o.y = fmaf(h.y, s, a.y) + b.y;
  o.z = fmaf(h.z, s, a.z) + b.z;
  o.w = fmaf(h.w, s, a.w) + b.w;
  if (RELU) {
    o.x = fmaxf(o.x, 0.f); o.y = fmaxf(o.y, 0.f);
    o.z = fmaxf(o.z, 0.f); o.w = fmaxf(o.w, 0.f);
  }
  *(float4*)&agg[(size_t)i * M + j] = o;
}

// ---------- fused pair MLP: logits[e] = MLP(concat(h2[p0],h2[p1])) ----------
// 64 pairs per tile. Layer a: [64x128]@[128x64] with 4x4 microtiles; layer b:
// [64x64]@[64x32]; layer c reduced with intra-wave shuffles. s1/s2 alias the
// feat region (dead after layer a). LDS ~78.4KB -> 2 blocks/CU.
__global__ __launch_bounds__(256, 2) void k_mlp(const float* __restrict__ h2,
    const int* __restrict__ p0, const int* __restrict__ p1,
    const float* __restrict__ Wa, const float* __restrict__ ba,
    const float* __restrict__ Wb, const float* __restrict__ bb,
    const float* __restrict__ Wc, const float* __restrict__ bc,
    float* __restrict__ logits, int ES) {
  __shared__ alignas(16) float sWa[128 * 68];   // [k][c] stride 68
  __shared__ alignas(16) float sWb[64 * 36];    // [k][c] stride 36
  __shared__ alignas(16) float sFeat[64 * 132]; // feat [p][k] stride 132; later s1(stride 68)+s2(stride 36)
  __shared__ float sWc[32], sba[64], sbb[32], sbc;
  const int t = threadIdx.x;
#pragma unroll
  for (int i = t * 4; i < 128 * 64; i += 1024) {
    int r = i >> 6, c = i & 63;
    *(float4*)&sWa[r * 68 + c] = *(const float4*)&Wa[i];
  }
#pragma unroll
  for (int i = t * 4; i < 64 * 32; i += 1024) {
    int r = i >> 5, c = i & 31;
    *(float4*)&sWb[r * 36 + c] = *(const float4*)&Wb[i];
  }
  if (t < 32) { sWc[t] = Wc[t]; sbb[t] = bb[t]; }
  if (t < 64) sba[t] = ba[t];
  if (t == 0) sbc = bc[0];

  const int rg = t >> 4, cg = t & 15;
  const int nTiles = (ES + 63) >> 6;
  for (int tile = blockIdx.x; tile < nTiles; tile += gridDim.x) {
    __syncthreads();  // feat region free; (1st iter) weights staged
    const int base = tile << 6;
    {  // gather: thread (p = t/4, q = t%4) loads 64B pieces of both rows
      int p = t >> 2, q = t & 3;
      int e = base + p; if (e >= ES) e = ES - 1;
      const float* r0p = h2 + (size_t)p0[e] * 64;
      const float* r1p = h2 + (size_t)p1[e] * 64;
#pragma unroll
      for (int i = 0; i < 4; i++) {
        int c = i * 16 + q * 4;
        *(float4*)&sFeat[p * 132 + c] = *(const float4*)&r0p[c];
        *(float4*)&sFeat[p * 132 + 64 + c] = *(const float4*)&r1p[c];
      }
    }
    __syncthreads();
    // layer a
    float acc[4][4] = {};
#pragma unroll 8
    for (int k0 = 0; k0 < 128; k0 += 4) {
      float4 av[4];
#pragma unroll
      for (int ri = 0; ri < 4; ri++) av[ri] = *(const float4*)&sFeat[(rg * 4 + ri) * 132 + k0];
      float4 wv[4];
#pragma unroll
      for (int kk = 0; kk < 4; kk++) wv[kk] = *(const float4*)&sWa[(k0 + kk) * 68 + cg * 4];
#pragma unroll
      for (int kk = 0; kk < 4; kk++)
#pragma unroll
        for (int ri = 0; ri < 4; ri++) {
          float a = ((const float*)&av[ri])[kk];
          acc[ri][0] = fmaf(a, wv[kk].x, acc[ri][0]);
          acc[ri][1] = fmaf(a, wv[kk].y, acc[ri][1]);
          acc[ri][2] = fmaf(a, wv[kk].z, acc[ri][2]);
          acc[ri][3] = fmaf(a, wv[kk].w, acc[ri][3]);
        }
    }
    __syncthreads();
#pragma unroll
    for (int ri = 0; ri < 4; ri++) {   // s1 = relu(acc+ba) -> sFeat[0..), stride 68
      float4 o;
      o.x = fmaxf(acc[ri][0] + sba[cg * 4 + 0], 0.f);
      o.y = fmaxf(acc[ri][1] + sba[cg * 4 + 1], 0.f);
      o.z = fmaxf(acc[ri][2] + sba[cg * 4 + 2], 0.f);
      o.w = fmaxf(acc[ri][3] + sba[cg * 4 + 3], 0.f);
      *(float4*)&sFeat[(rg * 4 + ri) * 68 + cg * 4] = o;
    }
    __syncthreads();
    // layer b
    float accb[4][2] = {};
#pragma unroll
    for (int k0 = 0; k0 < 64; k0 += 4) {
      float4 av[4];
#pragma unroll
      for (int ri = 0; ri < 4; ri++) av[ri] = *(const float4*)&sFeat[(rg * 4 + ri) * 68 + k0];
      float2 wv[4];
#pragma unroll
      for (int kk = 0; kk < 4; kk++) wv[kk] = *(const float2*)&sWb[(k0 + kk) * 36 + cg * 2];
#pragma unroll
      for (int kk = 0; kk < 4; kk++)
#pragma unroll
        for (int ri = 0; ri < 4; ri++) {
          float a = ((const float*)&av[ri])[kk];
          accb[ri][0] = fmaf(a, wv[kk].x, accb[ri][0]);
          accb[ri][1] = fmaf(a, wv[kk].y, accb[ri][1]);
        }
    }
    __syncthreads();
    float* sS2 = sFeat + 64 * 68;  // s2 region, stride 36
#pragma unroll
    for (int ri = 0; ri < 4; ri++) {
      float2 o;
      o.x = fmaxf(accb[ri][0] + sbb[cg * 2 + 0], 0.f);
      o.y = fmaxf(accb[ri][1] + sbb[cg * 2 + 1], 0.f);
      *(float2*)&sS2[(rg * 4 + ri) * 36 + cg * 2] = o;
    }
    __syncthreads();
    {  // layer c: thread (p,q) partial over j = q + 4*jj, shuffle-reduce over q
      int p = t >> 2, q = t & 3;
      float s = 0.f;
#pragma unroll
      for (int jj = 0; jj < 8; jj++) {
        int j = q + jj * 4;
        s = fmaf(sS2[p * 36 + j], sWc[j], s);
      }
      s += __shfl_down(s, 2);
      s += __shfl_down(s, 1);
      if (q == 0 && base + p < ES) logits[base + p] = s + sbc;
    }
  }
}

// ---------- segment softmax (edge_graph is sorted -> wave-uniform fast path) ----------
DEVINL unsigned fenc(float f) {
  unsigned u = __float_as_uint(f);
  return (u & 0x80000000u) ? ~u : (u | 0x80000000u);
}
DEVINL float fdec(unsigned u) {
  return (u & 0x80000000u) ? __uint_as_float(u & 0x7FFFFFFFu) : __uint_as_float(~u);
}

__global__ void k_initg(unsigned* gmaxU, float* gsum, int G) {
  int i = blockIdx.x * 256 + threadIdx.x;
  if (i < G) { gmaxU[i] = 0u; gsum[i] = 0.f; }
}
__global__ void k_segmax(const float* __restrict__ logits, const int* __restrict__ eg,
                         unsigned* __restrict__ gmaxU, int ES) {
  int i = blockIdx.x * 256 + threadIdx.x;
  bool valid = i < ES;
  int g = eg[valid ? i : (ES - 1)];
  unsigned key = valid ? fenc(logits[i]) : 0u;
  int g0 = __builtin_amdgcn_readfirstlane(g);
  if (__ballot(g == g0) == ~0ull) {
#pragma unroll
    for (int m = 32; m >= 1; m >>= 1) {
      unsigned o = (unsigned)__shfl_xor((int)key, m);
      key = key > o ? key : o;
    }
    if ((threadIdx.x & 63) == 0) atomicMax(&gmaxU[g0], key);
  } else {
    atomicMax(&gmaxU[g], key);
  }
}
__global__ void k_segexp(float* __restrict__ e_inout, const int* __restrict__ eg,
                         const unsigned* __restrict__ gmaxU, float* __restrict__ gsum,
                         int ES) {
  int i = blockIdx.x * 256 + threadIdx.x;
  bool valid = i < ES;
  int g = eg[valid ? i : (ES - 1)];
  float m = fdec(gmaxU[g]);
  float e = 0.f;
  if (valid) { e = expf(e_inout[i] - m); e_inout[i] = e; }
  int g0 = __builtin_amdgcn_readfirstlane(g);
  if (__ballot(g == g0) == ~0ull) {
#pragma unroll
    for (int msk = 32; msk >= 1; msk >>= 1) e += __shfl_xor(e, msk);
    if ((threadIdx.x & 63) == 0) atomicAdd(&gsum[g0], e);
  } else {
    atomicAdd(&gsum[g], e);
  }
}
__global__ void k_div(const float* __restrict__ e, const int* __restrict__ eg,
                      const float* __restrict__ gsum, float* __restrict__ out, int ES) {
  int i = blockIdx.x * 256 + threadIdx.x;
  if (i < ES) out[i] = e[i] / gsum[eg[i]];
}

// ---------------------------------------------------------------------------
extern "C" void kernel_launch(void* const* d_in, const int* in_sizes, int n_in,
                              void* d_out, int out_size, void* d_ws, size_t ws_size,
                              hipStream_t stream) {
  const float* x  = (const float*)d_in[0];
  const int* ei   = (const int*)d_in[1];
  const float* ew = (const float*)d_in[2];
  const int* pi   = (const int*)d_in[3];
  const int* eg   = (const int*)d_in[4];
  // d_in[5] = num_graphs (scalar on device); value fixed at 128 by problem setup
  const float* Wp = (const float*)d_in[6];
  const float* bp = (const float*)d_in[7];
  const float* W1 = (const float*)d_in[8];
  const float* b1 = (const float*)d_in[9];
  const float* W2 = (const float*)d_in[10];
  const float* b2 = (const float*)d_in[11];
  const float* Wa = (const float*)d_in[12];
  const float* ba = (const float*)d_in[13];
  const float* Wb = (const float*)d_in[14];
  const float* bb = (const float*)d_in[15];
  const float* Wc = (const float*)d_in[16];
  const float* bc = (const float*)d_in[17];

  const int N  = in_sizes[0] / 64;
  const int E  = in_sizes[2];
  const int ES = in_sizes[4];
  const int G  = 128;

  // workspace layout (floats): dinv[N] | normE[E] | gmaxU[128] | gsum[128] | A[N*128] | B[N*128]
  float* ws = (float*)d_ws;
  size_t o = 0;
  float* dinv = ws + o;  o += ((size_t)N + 31) & ~(size_t)31;
  float* normE = ws + o; o += ((size_t)E + 31) & ~(size_t)31;
  unsigned* gmaxU = (unsigned*)(ws + o); o += 128;
  float* gsum = ws + o;  o += 128;
  float* A = ws + o;     o += (size_t)N * 128;  // h0 -> agg1/h1 -> agg2/h2
  float* B = ws + o;     o += (size_t)N * 128;  // hw1 -> hw2 -> logits/e

  const int* row = ei;
  const int* col = ei + E;
  const int* p0 = pi;
  const int* p1 = pi + ES;
  float* out = (float*)d_out;

  const int gN = (N + 255) / 256;
  const int gE = (E + 255) / 256;
  k_deg_init<<<gN, 256, 0, stream>>>(dinv, N);
  k_deg_acc<<<gE, 256, 0, stream>>>(col, ew, dinv, E);
  k_deg_inv<<<gN, 256, 0, stream>>>(dinv, N);
  k_norm<<<gE, 256, 0, stream>>>(row, col, ew, dinv, normE, E);

  const int gRows = (N + 127) / 128;
  k_gemm<64, 128, true><<<gRows, 256, 0, stream>>>(x, Wp, bp, A, N);        // h0
  k_gemm<128, 128, false><<<gRows, 256, 0, stream>>>(A, W1, nullptr, B, N); // hw1
  hipMemsetAsync(A, 0, (size_t)N * 128 * sizeof(float), stream);
  k_scatter<128><<<(int)(((long long)E * 32 + 255) / 256), 256, 0, stream>>>(row, col, normE, B, A, E);
  k_finalize<128, true><<<(int)(((long long)N * 32 + 255) / 256), 256, 0, stream>>>(A, B, dinv, b1, N);
  k_gemm<128, 64, false><<<gRows, 256, 0, stream>>>(A, W2, nullptr, B, N);  // hw2
  hipMemsetAsync(A, 0, (size_t)N * 64 * sizeof(float), stream);
  k_scatter<64><<<(int)(((long long)E * 16 + 255) / 256), 256, 0, stream>>>(row, col, normE, B, A, E);
  k_finalize<64, false><<<(int)(((long long)N * 16 + 255) / 256), 256, 0, stream>>>(A, B, dinv, b2, N);

  const int nTiles = (ES + 63) / 64;
  const int gMlp = nTiles < 3125 ? nTiles : 3125;
  k_mlp<<<gMlp, 256, 0, stream>>>(A, p0, p1, Wa, ba, Wb, bb, Wc, bc, B, ES);

  k_initg<<<1, 256, 0, stream>>>(gmaxU, gsum, G);
  const int gES = (ES + 255) / 256;
  k_segmax<<<gES, 256, 0, stream>>>(B, eg, gmaxU, ES);
  k_segexp<<<gES, 256, 0, stream>>>(B, eg, gmaxU, gsum, ES);
  k_div<<<gES, 256, 0, stream>>>(B, eg, gsum, out, ES);
}

// Round 2
// 1729.085 us; speedup vs baseline: 2.3398x; 2.3398x over previous
//
#include <hip/hip_runtime.h>
#include <hip/hip_bf16.h>
#include <cstdint>

#define DEVINL __device__ __forceinline__

// ---------------------------------------------------------------------------
// 2-layer GCN (gcn_norm w/ self-loops) -> per-pair MLP -> per-graph softmax.
// R2: atomic scatter (1.6ms+0.8ms, 2GB atomic WRITE traffic) replaced by a
// CSR-by-destination gather built once per call. All fp32.
// ---------------------------------------------------------------------------

// ---------- CSR build ----------
__global__ void k_hist(const int* __restrict__ col, int* __restrict__ cnt, int E) {
  int e = blockIdx.x * 256 + threadIdx.x;
  if (e < E) atomicAdd(&cnt[col[e]], 1);
}

// block-level exclusive scan (Hillis-Steele), 256/block
__global__ void k_scan1(const int* __restrict__ cnt, int* __restrict__ start,
                        int* __restrict__ bsum, int N) {
  __shared__ int s[256];
  int t = threadIdx.x;
  int i = blockIdx.x * 256 + t;
  int v = (i < N) ? cnt[i] : 0;
  s[t] = v; __syncthreads();
  int x = v;
#pragma unroll
  for (int off = 1; off < 256; off <<= 1) {
    int y = (t >= off) ? s[t - off] : 0;
    __syncthreads();
    x += y; s[t] = x;
    __syncthreads();
  }
  if (i < N) start[i] = x - v;             // block-local exclusive
  if (t == 255) bsum[blockIdx.x] = x;      // block total
}
__global__ void k_scan2(const int* __restrict__ bsum, int* __restrict__ boff, int nb) {
  __shared__ int s[512];
  int t = threadIdx.x;
  int v = (t < nb) ? bsum[t] : 0;
  s[t] = v; __syncthreads();
  int x = v;
#pragma unroll
  for (int off = 1; off < 512; off <<= 1) {
    int y = (t >= off) ? s[t - off] : 0;
    __syncthreads();
    x += y; s[t] = x;
    __syncthreads();
  }
  if (t < nb) boff[t] = x - v;             // exclusive block offsets
}
__global__ void k_scan3(int* __restrict__ start, const int* __restrict__ boff, int N) {
  int i = blockIdx.x * 256 + threadIdx.x;
  if (i < N) start[i] += boff[blockIdx.x];
}

// fill: mutates start[v] from exclusive-prefix to inclusive-end.
// afterwards: begin(v) = (v? start[v-1] : 0), end(v) = start[v].
__global__ void k_fill(const int* __restrict__ row, const int* __restrict__ col,
                       const float* __restrict__ w, int* __restrict__ start,
                       int2* __restrict__ pk, int E) {
  int e = blockIdx.x * 256 + threadIdx.x;
  if (e >= E) return;
  int c = col[e];
  int pos = atomicAdd(&start[c], 1);
  pk[pos] = make_int2(row[e], __float_as_int(w[e]));
}

// dinv[v] = rsqrt(1 + sum of edge weights into v)   (self-loop weight 1)
__global__ void k_dinv_csr(const int* __restrict__ start, const int2* __restrict__ pk,
                           float* __restrict__ dinv, int N) {
  int v = blockIdx.x * 256 + threadIdx.x;
  if (v >= N) return;
  int b = v ? start[v - 1] : 0;
  int en = start[v];
  float s = 1.0f;
  for (int i = b; i < en; i++) s += __int_as_float(pk[i].y);
  dinv[v] = rsqrtf(s);
}

// pk[i].y (= w) *= dinv[row]
__global__ void k_permnorm(int2* __restrict__ pk, const float* __restrict__ dinv, int E) {
  int i = blockIdx.x * 256 + threadIdx.x;
  if (i >= E) return;
  int2 p = pk[i];
  p.y = __float_as_int(__int_as_float(p.y) * dinv[p.x]);
  pk[i] = p;
}

// ---------- tiled fp32 GEMM: C[N,M] = A[N,K] @ W[K,M] (+bias) ----------
template<int K, int M, bool BIAS>
__global__ __launch_bounds__(256, 2) void k_gemm(const float* __restrict__ A,
                                                 const float* __restrict__ W,
                                                 const float* __restrict__ bias,
                                                 float* __restrict__ C, int N) {
  constexpr int KC = 64;
  constexpr int NB = M / 64;
  __shared__ alignas(16) float sA[128 * 68];       // [r][k], stride 68
  __shared__ alignas(16) float sW[KC * (M + 4)];   // [k][c], stride M+4
  const int t = threadIdx.x;
  const int rg = t >> 4, cg = t & 15;
  const int r0 = blockIdx.x * 128;
  float acc[NB][8][4] = {};
  for (int kc = 0; kc < K; kc += KC) {
    __syncthreads();
#pragma unroll
    for (int i = 0; i < 8; i++) {           // stage A: 128x64 floats
      int idx = t * 4 + i * 1024;
      int r = idx >> 6, k = idx & 63;
      int gr = r0 + r;
      float4 v = make_float4(0.f, 0.f, 0.f, 0.f);
      if (gr < N) v = *(const float4*)&A[(size_t)gr * K + kc + k];
      *(float4*)&sA[r * 68 + k] = v;
    }
#pragma unroll
    for (int i = 0; i < KC * M / 1024; i++) {  // stage W chunk
      int idx = t * 4 + i * 1024;
      int r = idx / M, c = idx % M;
      *(float4*)&sW[r * (M + 4) + c] = *(const float4*)&W[(size_t)(kc + r) * M + c];
    }
    __syncthreads();
#pragma unroll
    for (int k0 = 0; k0 < KC; k0 += 4) {
      float4 av[8];
#pragma unroll
      for (int ri = 0; ri < 8; ri++) av[ri] = *(const float4*)&sA[(rg + 16 * ri) * 68 + k0];
      float4 wv[4][NB];
#pragma unroll
      for (int kk = 0; kk < 4; kk++)
#pragma unroll
        for (int b = 0; b < NB; b++)
          wv[kk][b] = *(const float4*)&sW[(k0 + kk) * (M + 4) + b * 64 + cg * 4];
#pragma unroll
      for (int kk = 0; kk < 4; kk++)
#pragma unroll
        for (int ri = 0; ri < 8; ri++) {
          float a = ((const float*)&av[ri])[kk];
#pragma unroll
          for (int b = 0; b < NB; b++) {
            acc[b][ri][0] = fmaf(a, wv[kk][b].x, acc[b][ri][0]);
            acc[b][ri][1] = fmaf(a, wv[kk][b].y, acc[b][ri][1]);
            acc[b][ri][2] = fmaf(a, wv[kk][b].z, acc[b][ri][2]);
            acc[b][ri][3] = fmaf(a, wv[kk][b].w, acc[b][ri][3]);
          }
        }
    }
  }
#pragma unroll
  for (int ri = 0; ri < 8; ri++) {
    int rrow = r0 + rg + 16 * ri;
    if (rrow < N) {
#pragma unroll
      for (int b = 0; b < NB; b++) {
        float4 o;
        o.x = acc[b][ri][0]; o.y = acc[b][ri][1]; o.z = acc[b][ri][2]; o.w = acc[b][ri][3];
        if (BIAS) {
          float4 bv = *(const float4*)&bias[b * 64 + cg * 4];
          o.x += bv.x; o.y += bv.y; o.z += bv.z; o.w += bv.w;
        }
        *(float4*)&C[(size_t)rrow * M + b * 64 + cg * 4] = o;
      }
    }
  }
}

// ---------- CSR gather + finalize: h[v] = act(dinv*sum + dinv^2*hw[v] + b) ----------
// L = M/4 lanes per node, each lane owns one float4 column slice.
template<int M, bool RELU>
__global__ void k_gather(const int* __restrict__ start, const int2* __restrict__ pk,
                         const float* __restrict__ hw, const float* __restrict__ dinv,
                         const float* __restrict__ bias, float* __restrict__ hout, int N) {
  constexpr int L = M / 4;               // lanes per node
  constexpr int NPB = 256 / L;           // nodes per block
  const int t = threadIdx.x;
  const int v = blockIdx.x * NPB + t / L;
  if (v >= N) return;
  const int j = (t % L) * 4;
  const int b = v ? start[v - 1] : 0;
  const int en = start[v];
  float4 acc = make_float4(0.f, 0.f, 0.f, 0.f);
  int i = b;
  for (; i + 1 < en; i += 2) {          // 2x unroll for memory-level parallelism
    int2 p0 = pk[i], p1 = pk[i + 1];
    float n0 = __int_as_float(p0.y), n1 = __int_as_float(p1.y);
    float4 h0 = *(const float4*)&hw[(size_t)p0.x * M + j];
    float4 h1 = *(const float4*)&hw[(size_t)p1.x * M + j];
    acc.x = fmaf(n0, h0.x, acc.x); acc.y = fmaf(n0, h0.y, acc.y);
    acc.z = fmaf(n0, h0.z, acc.z); acc.w = fmaf(n0, h0.w, acc.w);
    acc.x = fmaf(n1, h1.x, acc.x); acc.y = fmaf(n1, h1.y, acc.y);
    acc.z = fmaf(n1, h1.z, acc.z); acc.w = fmaf(n1, h1.w, acc.w);
  }
  if (i < en) {
    int2 p = pk[i];
    float n = __int_as_float(p.y);
    float4 h = *(const float4*)&hw[(size_t)p.x * M + j];
    acc.x = fmaf(n, h.x, acc.x); acc.y = fmaf(n, h.y, acc.y);
    acc.z = fmaf(n, h.z, acc.z); acc.w = fmaf(n, h.w, acc.w);
  }
  const float d = dinv[v];
  const float s = d * d;
  float4 hv = *(const float4*)&hw[(size_t)v * M + j];
  float4 bv = *(const float4*)&bias[j];
  float4 o;
  o.x = fmaf(d, acc.x, fmaf(s, hv.x, bv.x));
  o.y = fmaf(d, acc.y, fmaf(s, hv.y, bv.y));
  o.z = fmaf(d, acc.z, fmaf(s, hv.z, bv.z));
  o.w = fmaf(d, acc.w, fmaf(s, hv.w, bv.w));
  if (RELU) {
    o.x = fmaxf(o.x, 0.f); o.y = fmaxf(o.y, 0.f);
    o.z = fmaxf(o.z, 0.f); o.w = fmaxf(o.w, 0.f);
  }
  *(float4*)&hout[(size_t)v * M + j] = o;
}

// ---------- fused pair MLP ----------
__global__ __launch_bounds__(256, 2) void k_mlp(const float* __restrict__ h2,
    const int* __restrict__ p0, const int* __restrict__ p1,
    const float* __restrict__ Wa, const float* __restrict__ ba,
    const float* __restrict__ Wb, const float* __restrict__ bb,
    const float* __restrict__ Wc, const float* __restrict__ bc,
    float* __restrict__ logits, int ES) {
  __shared__ alignas(16) float sWa[128 * 68];   // [k][c] stride 68
  __shared__ alignas(16) float sWb[64 * 36];    // [k][c] stride 36
  __shared__ alignas(16) float sFeat[64 * 132]; // feat [p][k] stride 132; later s1(68)+s2(36)
  __shared__ float sWc[32], sba[64], sbb[32], sbc;
  const int t = threadIdx.x;
#pragma unroll
  for (int i = t * 4; i < 128 * 64; i += 1024) {
    int r = i >> 6, c = i & 63;
    *(float4*)&sWa[r * 68 + c] = *(const float4*)&Wa[i];
  }
#pragma unroll
  for (int i = t * 4; i < 64 * 32; i += 1024) {
    int r = i >> 5, c = i & 31;
    *(float4*)&sWb[r * 36 + c] = *(const float4*)&Wb[i];
  }
  if (t < 32) { sWc[t] = Wc[t]; sbb[t] = bb[t]; }
  if (t < 64) sba[t] = ba[t];
  if (t == 0) sbc = bc[0];

  const int rg = t >> 4, cg = t & 15;
  const int nTiles = (ES + 63) >> 6;
  for (int tile = blockIdx.x; tile < nTiles; tile += gridDim.x) {
    __syncthreads();
    const int base = tile << 6;
    {  // gather pair rows
      int p = t >> 2, q = t & 3;
      int e = base + p; if (e >= ES) e = ES - 1;
      const float* r0p = h2 + (size_t)p0[e] * 64;
      const float* r1p = h2 + (size_t)p1[e] * 64;
#pragma unroll
      for (int i = 0; i < 4; i++) {
        int c = i * 16 + q * 4;
        *(float4*)&sFeat[p * 132 + c] = *(const float4*)&r0p[c];
        *(float4*)&sFeat[p * 132 + 64 + c] = *(const float4*)&r1p[c];
      }
    }
    __syncthreads();
    float acc[4][4] = {};
#pragma unroll 8
    for (int k0 = 0; k0 < 128; k0 += 4) {
      float4 av[4];
#pragma unroll
      for (int ri = 0; ri < 4; ri++) av[ri] = *(const float4*)&sFeat[(rg * 4 + ri) * 132 + k0];
      float4 wv[4];
#pragma unroll
      for (int kk = 0; kk < 4; kk++) wv[kk] = *(const float4*)&sWa[(k0 + kk) * 68 + cg * 4];
#pragma unroll
      for (int kk = 0; kk < 4; kk++)
#pragma unroll
        for (int ri = 0; ri < 4; ri++) {
          float a = ((const float*)&av[ri])[kk];
          acc[ri][0] = fmaf(a, wv[kk].x, acc[ri][0]);
          acc[ri][1] = fmaf(a, wv[kk].y, acc[ri][1]);
          acc[ri][2] = fmaf(a, wv[kk].z, acc[ri][2]);
          acc[ri][3] = fmaf(a, wv[kk].w, acc[ri][3]);
        }
    }
    __syncthreads();
#pragma unroll
    for (int ri = 0; ri < 4; ri++) {
      float4 o;
      o.x = fmaxf(acc[ri][0] + sba[cg * 4 + 0], 0.f);
      o.y = fmaxf(acc[ri][1] + sba[cg * 4 + 1], 0.f);
      o.z = fmaxf(acc[ri][2] + sba[cg * 4 + 2], 0.f);
      o.w = fmaxf(acc[ri][3] + sba[cg * 4 + 3], 0.f);
      *(float4*)&sFeat[(rg * 4 + ri) * 68 + cg * 4] = o;
    }
    __syncthreads();
    float accb[4][2] = {};
#pragma unroll
    for (int k0 = 0; k0 < 64; k0 += 4) {
      float4 av[4];
#pragma unroll
      for (int ri = 0; ri < 4; ri++) av[ri] = *(const float4*)&sFeat[(rg * 4 + ri) * 68 + k0];
      float2 wv[4];
#pragma unroll
      for (int kk = 0; kk < 4; kk++) wv[kk] = *(const float2*)&sWb[(k0 + kk) * 36 + cg * 2];
#pragma unroll
      for (int kk = 0; kk < 4; kk++)
#pragma unroll
        for (int ri = 0; ri < 4; ri++) {
          float a = ((const float*)&av[ri])[kk];
          accb[ri][0] = fmaf(a, wv[kk].x, accb[ri][0]);
          accb[ri][1] = fmaf(a, wv[kk].y, accb[ri][1]);
        }
    }
    __syncthreads();
    float* sS2 = sFeat + 64 * 68;
#pragma unroll
    for (int ri = 0; ri < 4; ri++) {
      float2 o;
      o.x = fmaxf(accb[ri][0] + sbb[cg * 2 + 0], 0.f);
      o.y = fmaxf(accb[ri][1] + sbb[cg * 2 + 1], 0.f);
      *(float2*)&sS2[(rg * 4 + ri) * 36 + cg * 2] = o;
    }
    __syncthreads();
    {
      int p = t >> 2, q = t & 3;
      float s = 0.f;
#pragma unroll
      for (int jj = 0; jj < 8; jj++) {
        int j = q + jj * 4;
        s = fmaf(sS2[p * 36 + j], sWc[j], s);
      }
      s += __shfl_down(s, 2);
      s += __shfl_down(s, 1);
      if (q == 0 && base + p < ES) logits[base + p] = s + sbc;
    }
  }
}

// ---------- segment softmax (edge_graph sorted -> wave-uniform fast path) ----------
DEVINL unsigned fenc(float f) {
  unsigned u = __float_as_uint(f);
  return (u & 0x80000000u) ? ~u : (u | 0x80000000u);
}
DEVINL float fdec(unsigned u) {
  return (u & 0x80000000u) ? __uint_as_float(u & 0x7FFFFFFFu) : __uint_as_float(~u);
}

__global__ void k_initg(unsigned* gmaxU, float* gsum, int G) {
  int i = blockIdx.x * 256 + threadIdx.x;
  if (i < G) { gmaxU[i] = 0u; gsum[i] = 0.f; }
}
__global__ void k_segmax(const float* __restrict__ logits, const int* __restrict__ eg,
                         unsigned* __restrict__ gmaxU, int ES) {
  int i = blockIdx.x * 256 + threadIdx.x;
  bool valid = i < ES;
  int g = eg[valid ? i : (ES - 1)];
  unsigned key = valid ? fenc(logits[i]) : 0u;
  int g0 = __builtin_amdgcn_readfirstlane(g);
  if (__ballot(g == g0) == ~0ull) {
#pragma unroll
    for (int m = 32; m >= 1; m >>= 1) {
      unsigned o = (unsigned)__shfl_xor((int)key, m);
      key = key > o ? key : o;
    }
    if ((threadIdx.x & 63) == 0) atomicMax(&gmaxU[g0], key);
  } else {
    atomicMax(&gmaxU[g], key);
  }
}
__global__ void k_segexp(float* __restrict__ e_inout, const int* __restrict__ eg,
                         const unsigned* __restrict__ gmaxU, float* __restrict__ gsum,
                         int ES) {
  int i = blockIdx.x * 256 + threadIdx.x;
  bool valid = i < ES;
  int g = eg[valid ? i : (ES - 1)];
  float m = fdec(gmaxU[g]);
  float e = 0.f;
  if (valid) { e = expf(e_inout[i] - m); e_inout[i] = e; }
  int g0 = __builtin_amdgcn_readfirstlane(g);
  if (__ballot(g == g0) == ~0ull) {
#pragma unroll
    for (int msk = 32; msk >= 1; msk >>= 1) e += __shfl_xor(e, msk);
    if ((threadIdx.x & 63) == 0) atomicAdd(&gsum[g0], e);
  } else {
    atomicAdd(&gsum[g], e);
  }
}
__global__ void k_div(const float* __restrict__ e, const int* __restrict__ eg,
                      const float* __restrict__ gsum, float* __restrict__ out, int ES) {
  int i = blockIdx.x * 256 + threadIdx.x;
  if (i < ES) out[i] = e[i] / gsum[eg[i]];
}

// ---------------------------------------------------------------------------
extern "C" void kernel_launch(void* const* d_in, const int* in_sizes, int n_in,
                              void* d_out, int out_size, void* d_ws, size_t ws_size,
                              hipStream_t stream) {
  const float* x  = (const float*)d_in[0];
  const int* ei   = (const int*)d_in[1];
  const float* ew = (const float*)d_in[2];
  const int* pi   = (const int*)d_in[3];
  const int* eg   = (const int*)d_in[4];
  const float* Wp = (const float*)d_in[6];
  const float* bp = (const float*)d_in[7];
  const float* W1 = (const float*)d_in[8];
  const float* b1 = (const float*)d_in[9];
  const float* W2 = (const float*)d_in[10];
  const float* b2 = (const float*)d_in[11];
  const float* Wa = (const float*)d_in[12];
  const float* ba = (const float*)d_in[13];
  const float* Wb = (const float*)d_in[14];
  const float* bb = (const float*)d_in[15];
  const float* Wc = (const float*)d_in[16];
  const float* bc = (const float*)d_in[17];

  const int N  = in_sizes[0] / 64;
  const int E  = in_sizes[2];
  const int ES = in_sizes[4];
  const int G  = 128;

  // workspace (floats):
  // cnt[N] (-> dinv after scan) | start[N] | bsum[512] | boff[512] |
  // pk[E] int2 | A[N*128] | B[N*128]
  float* ws = (float*)d_ws;
  size_t o = 0;
  int* cnt = (int*)(ws + o);   o += ((size_t)N + 31) & ~(size_t)31;
  float* dinv = (float*)cnt;   // cnt is dead after scan1; reuse as dinv
  int* start = (int*)(ws + o); o += ((size_t)N + 31) & ~(size_t)31;
  int* bsum = (int*)(ws + o);  o += 512;
  int* boff = (int*)(ws + o);  o += 512;
  int2* pk = (int2*)(ws + o);  o += (size_t)E * 2;
  float* A = ws + o;           o += (size_t)N * 128;  // h0 -> h1 -> h2
  float* B = ws + o;           o += (size_t)N * 128;  // hw1 -> hw2 -> logits/e

  const int* row = ei;
  const int* col = ei + E;
  const int* p0 = pi;
  const int* p1 = pi + ES;
  float* out = (float*)d_out;

  const int gN = (N + 255) / 256;
  const int gE = (E + 255) / 256;
  const int nb = gN;  // scan blocks (N/256 = 391 <= 512)

  // ---- CSR build (shared by both GCN layers) ----
  hipMemsetAsync(cnt, 0, (size_t)N * sizeof(int), stream);
  k_hist<<<gE, 256, 0, stream>>>(col, cnt, E);
  k_scan1<<<nb, 256, 0, stream>>>(cnt, start, bsum, N);
  k_scan2<<<1, 512, 0, stream>>>(bsum, boff, nb);
  k_scan3<<<nb, 256, 0, stream>>>(start, boff, N);
  k_fill<<<gE, 256, 0, stream>>>(row, col, ew, start, pk, E);
  k_dinv_csr<<<gN, 256, 0, stream>>>(start, pk, dinv, N);
  k_permnorm<<<gE, 256, 0, stream>>>(pk, dinv, E);

  // ---- GCN layers ----
  const int gRows = (N + 127) / 128;
  k_gemm<64, 128, true><<<gRows, 256, 0, stream>>>(x, Wp, bp, A, N);        // h0
  k_gemm<128, 128, false><<<gRows, 256, 0, stream>>>(A, W1, nullptr, B, N); // hw1
  k_gather<128, true><<<(N + 7) / 8, 256, 0, stream>>>(start, pk, B, dinv, b1, A, N);
  k_gemm<128, 64, false><<<gRows, 256, 0, stream>>>(A, W2, nullptr, B, N);  // hw2
  k_gather<64, false><<<(N + 15) / 16, 256, 0, stream>>>(start, pk, B, dinv, b2, A, N);

  // ---- pair MLP ----
  const int nTiles = (ES + 63) / 64;
  const int gMlp = nTiles < 3125 ? nTiles : 3125;
  k_mlp<<<gMlp, 256, 0, stream>>>(A, p0, p1, Wa, ba, Wb, bb, Wc, bc, B, ES);

  // ---- segment softmax ----
  k_initg<<<1, 256, 0, stream>>>((unsigned*)bsum, (float*)boff, G);
  const int gES = (ES + 255) / 256;
  k_segmax<<<gES, 256, 0, stream>>>(B, eg, (unsigned*)bsum, ES);
  k_segexp<<<gES, 256, 0, stream>>>(B, eg, (unsigned*)bsum, (float*)boff, ES);
  k_div<<<gES, 256, 0, stream>>>(B, eg, (float*)boff, out, ES);
}

// Round 3
// 1320.176 us; speedup vs baseline: 3.0646x; 1.3097x over previous
//
#include <hip/hip_runtime.h>
#include <hip/hip_bf16.h>
#include <cstdint>

#define DEVINL __device__ __forceinline__

// ---------------------------------------------------------------------------
// 2-layer GCN (gcn_norm w/ self-loops) -> per-pair MLP -> per-graph softmax.
// R3: algebraic refactor.
//   hw1 = x @ (Wp@W1) + bp@W1                  (h0 eliminated)
//   h1  = relu(Agg(hw1) + b1)
//   U   = Agg(h1 @ (W2@[Wa0|Wa1])) + [b2@Wa0+ba | b2@Wa1]   (per-NODE, not per-edge)
//   logit_e = relu(U0[p0]+U1[p1]) @ Wb .. @ Wc (per-edge work: 64-add + 64x32 + 32-dot)
//   softmax: one kernel, 128 blocks, segment bounds via binary search (eg sorted)
// ---------------------------------------------------------------------------

// ---------- CSR build ----------
__global__ void k_hist(const int* __restrict__ col, int* __restrict__ cnt, int E) {
  int e = blockIdx.x * 256 + threadIdx.x;
  if (e < E) atomicAdd(&cnt[col[e]], 1);
}

__global__ void k_scan1(const int* __restrict__ cnt, int* __restrict__ start,
                        int* __restrict__ bsum, int N) {
  __shared__ int s[256];
  int t = threadIdx.x;
  int i = blockIdx.x * 256 + t;
  int v = (i < N) ? cnt[i] : 0;
  s[t] = v; __syncthreads();
  int x = v;
#pragma unroll
  for (int off = 1; off < 256; off <<= 1) {
    int y = (t >= off) ? s[t - off] : 0;
    __syncthreads();
    x += y; s[t] = x;
    __syncthreads();
  }
  if (i < N) start[i] = x - v;
  if (t == 255) bsum[blockIdx.x] = x;
}
__global__ void k_scan2(const int* __restrict__ bsum, int* __restrict__ boff, int nb) {
  __shared__ int s[512];
  int t = threadIdx.x;
  int v = (t < nb) ? bsum[t] : 0;
  s[t] = v; __syncthreads();
  int x = v;
#pragma unroll
  for (int off = 1; off < 512; off <<= 1) {
    int y = (t >= off) ? s[t - off] : 0;
    __syncthreads();
    x += y; s[t] = x;
    __syncthreads();
  }
  if (t < nb) boff[t] = x - v;
}
__global__ void k_scan3(int* __restrict__ start, const int* __restrict__ boff, int N) {
  int i = blockIdx.x * 256 + threadIdx.x;
  if (i < N) start[i] += boff[blockIdx.x];
}

// after k_fill: begin(v) = (v? start[v-1]:0), end(v) = start[v]
__global__ void k_fill(const int* __restrict__ row, const int* __restrict__ col,
                       const float* __restrict__ w, int* __restrict__ start,
                       int2* __restrict__ pk, int E) {
  int e = blockIdx.x * 256 + threadIdx.x;
  if (e >= E) return;
  int c = col[e];
  int pos = atomicAdd(&start[c], 1);
  pk[pos] = make_int2(row[e], __float_as_int(w[e]));
}

__global__ void k_dinv_csr(const int* __restrict__ start, const int2* __restrict__ pk,
                           float* __restrict__ dinv, int N) {
  int v = blockIdx.x * 256 + threadIdx.x;
  if (v >= N) return;
  int b = v ? start[v - 1] : 0;
  int en = start[v];
  float s = 1.0f;
  for (int i = b; i < en; i++) s += __int_as_float(pk[i].y);
  dinv[v] = rsqrtf(s);
}

__global__ void k_permnorm(int2* __restrict__ pk, const float* __restrict__ dinv, int E) {
  int i = blockIdx.x * 256 + threadIdx.x;
  if (i >= E) return;
  int2 p = pk[i];
  p.y = __float_as_int(__int_as_float(p.y) * dinv[p.x]);
  pk[i] = p;
}

// ---------- weight folding (tiny, once per call) ----------
// Wfuse[64,128] = Wp@W1 ; bfuse[128] = bp@W1
// Mcat[128,128] = [W2@Wa0 | W2@Wa1] ; bU[128] = [b2@Wa0 + ba | b2@Wa1]
__global__ void k_prep(const float* __restrict__ Wp, const float* __restrict__ bp,
                       const float* __restrict__ W1,
                       const float* __restrict__ W2, const float* __restrict__ Wa,
                       const float* __restrict__ ba, const float* __restrict__ b2,
                       float* __restrict__ Wfuse, float* __restrict__ bfuse,
                       float* __restrict__ Mcat, float* __restrict__ bU) {
  int id = blockIdx.x * 256 + threadIdx.x;
  if (id < 8192) {                      // Wfuse[i,j], i<64, j<128
    int i = id >> 7, j = id & 127;
    float s = 0.f;
    for (int k = 0; k < 128; k++) s = fmaf(Wp[i * 128 + k], W1[k * 128 + j], s);
    Wfuse[id] = s;
  } else if (id < 8320) {               // bfuse[j]
    int j = id - 8192;
    float s = 0.f;
    for (int k = 0; k < 128; k++) s = fmaf(bp[k], W1[k * 128 + j], s);
    bfuse[j] = s;
  } else if (id < 8320 + 16384) {       // Mcat[i,j], i<128, j<128
    int m = id - 8320;
    int i = m >> 7, j = m & 127;
    int jj = j & 63, koff = (j < 64) ? 0 : 64;
    float s = 0.f;
    for (int k = 0; k < 64; k++) s = fmaf(W2[i * 64 + k], Wa[(koff + k) * 64 + jj], s);
    Mcat[i * 128 + j] = s;
  } else if (id < 8320 + 16384 + 128) { // bU[j]
    int j = id - 8320 - 16384;
    int jj = j & 63, koff = (j < 64) ? 0 : 64;
    float s = (j < 64) ? ba[j] : 0.f;
    for (int k = 0; k < 64; k++) s = fmaf(b2[k], Wa[(koff + k) * 64 + jj], s);
    bU[j] = s;
  }
}

// ---------- tiled fp32 GEMM: C[N,M] = A[N,K] @ W[K,M] (+bias) ----------
template<int K, int M, bool BIAS>
__global__ __launch_bounds__(256, 2) void k_gemm(const float* __restrict__ A,
                                                 const float* __restrict__ W,
                                                 const float* __restrict__ bias,
                                                 float* __restrict__ C, int N) {
  constexpr int KC = 64;
  constexpr int NB = M / 64;
  __shared__ alignas(16) float sA[128 * 68];
  __shared__ alignas(16) float sW[KC * (M + 4)];
  const int t = threadIdx.x;
  const int rg = t >> 4, cg = t & 15;
  const int r0 = blockIdx.x * 128;
  float acc[NB][8][4] = {};
  for (int kc = 0; kc < K; kc += KC) {
    __syncthreads();
#pragma unroll
    for (int i = 0; i < 8; i++) {
      int idx = t * 4 + i * 1024;
      int r = idx >> 6, k = idx & 63;
      int gr = r0 + r;
      float4 v = make_float4(0.f, 0.f, 0.f, 0.f);
      if (gr < N) v = *(const float4*)&A[(size_t)gr * K + kc + k];
      *(float4*)&sA[r * 68 + k] = v;
    }
#pragma unroll
    for (int i = 0; i < KC * M / 1024; i++) {
      int idx = t * 4 + i * 1024;
      int r = idx / M, c = idx % M;
      *(float4*)&sW[r * (M + 4) + c] = *(const float4*)&W[(size_t)(kc + r) * M + c];
    }
    __syncthreads();
#pragma unroll
    for (int k0 = 0; k0 < KC; k0 += 4) {
      float4 av[8];
#pragma unroll
      for (int ri = 0; ri < 8; ri++) av[ri] = *(const float4*)&sA[(rg + 16 * ri) * 68 + k0];
      float4 wv[4][NB];
#pragma unroll
      for (int kk = 0; kk < 4; kk++)
#pragma unroll
        for (int b = 0; b < NB; b++)
          wv[kk][b] = *(const float4*)&sW[(k0 + kk) * (M + 4) + b * 64 + cg * 4];
#pragma unroll
      for (int kk = 0; kk < 4; kk++)
#pragma unroll
        for (int ri = 0; ri < 8; ri++) {
          float a = ((const float*)&av[ri])[kk];
#pragma unroll
          for (int b = 0; b < NB; b++) {
            acc[b][ri][0] = fmaf(a, wv[kk][b].x, acc[b][ri][0]);
            acc[b][ri][1] = fmaf(a, wv[kk][b].y, acc[b][ri][1]);
            acc[b][ri][2] = fmaf(a, wv[kk][b].z, acc[b][ri][2]);
            acc[b][ri][3] = fmaf(a, wv[kk][b].w, acc[b][ri][3]);
          }
        }
    }
  }
#pragma unroll
  for (int ri = 0; ri < 8; ri++) {
    int rrow = r0 + rg + 16 * ri;
    if (rrow < N) {
#pragma unroll
      for (int b = 0; b < NB; b++) {
        float4 o;
        o.x = acc[b][ri][0]; o.y = acc[b][ri][1]; o.z = acc[b][ri][2]; o.w = acc[b][ri][3];
        if (BIAS) {
          float4 bv = *(const float4*)&bias[b * 64 + cg * 4];
          o.x += bv.x; o.y += bv.y; o.z += bv.z; o.w += bv.w;
        }
        *(float4*)&C[(size_t)rrow * M + b * 64 + cg * 4] = o;
      }
    }
  }
}

// ---------- CSR gather: h[v] = act(dinv*sum + dinv^2*hw[v] + bias) ----------
template<int M, bool RELU>
__global__ void k_gather(const int* __restrict__ start, const int2* __restrict__ pk,
                         const float* __restrict__ hw, const float* __restrict__ dinv,
                         const float* __restrict__ bias, float* __restrict__ hout, int N) {
  constexpr int L = M / 4;
  constexpr int NPB = 256 / L;
  const int t = threadIdx.x;
  const int v = blockIdx.x * NPB + t / L;
  if (v >= N) return;
  const int j = (t % L) * 4;
  const int b = v ? start[v - 1] : 0;
  const int en = start[v];
  float4 acc = make_float4(0.f, 0.f, 0.f, 0.f);
  int i = b;
  for (; i + 1 < en; i += 2) {
    int2 p0 = pk[i], p1 = pk[i + 1];
    float n0 = __int_as_float(p0.y), n1 = __int_as_float(p1.y);
    float4 h0 = *(const float4*)&hw[(size_t)p0.x * M + j];
    float4 h1 = *(const float4*)&hw[(size_t)p1.x * M + j];
    acc.x = fmaf(n0, h0.x, acc.x); acc.y = fmaf(n0, h0.y, acc.y);
    acc.z = fmaf(n0, h0.z, acc.z); acc.w = fmaf(n0, h0.w, acc.w);
    acc.x = fmaf(n1, h1.x, acc.x); acc.y = fmaf(n1, h1.y, acc.y);
    acc.z = fmaf(n1, h1.z, acc.z); acc.w = fmaf(n1, h1.w, acc.w);
  }
  if (i < en) {
    int2 p = pk[i];
    float n = __int_as_float(p.y);
    float4 h = *(const float4*)&hw[(size_t)p.x * M + j];
    acc.x = fmaf(n, h.x, acc.x); acc.y = fmaf(n, h.y, acc.y);
    acc.z = fmaf(n, h.z, acc.z); acc.w = fmaf(n, h.w, acc.w);
  }
  const float d = dinv[v];
  const float s = d * d;
  float4 hv = *(const float4*)&hw[(size_t)v * M + j];
  float4 bv = *(const float4*)&bias[j];
  float4 o;
  o.x = fmaf(d, acc.x, fmaf(s, hv.x, bv.x));
  o.y = fmaf(d, acc.y, fmaf(s, hv.y, bv.y));
  o.z = fmaf(d, acc.z, fmaf(s, hv.z, bv.z));
  o.w = fmaf(d, acc.w, fmaf(s, hv.w, bv.w));
  if (RELU) {
    o.x = fmaxf(o.x, 0.f); o.y = fmaxf(o.y, 0.f);
    o.z = fmaxf(o.z, 0.f); o.w = fmaxf(o.w, 0.f);
  }
  *(float4*)&hout[(size_t)v * M + j] = o;
}

// ---------- per-edge kernel: logit = relu(U0[p0]+U1[p1]) @ Wb(relu) @ Wc ----------
// 64 edges per block, 256 threads.
__global__ __launch_bounds__(256) void k_edge(const float* __restrict__ U,
    const int* __restrict__ p0, const int* __restrict__ p1,
    const float* __restrict__ Wb, const float* __restrict__ bb,
    const float* __restrict__ Wc, const float* __restrict__ bc,
    float* __restrict__ logits, int ES) {
  __shared__ alignas(16) float sWb[64 * 36];   // [k][c] stride 36
  __shared__ alignas(16) float sS1[64 * 68];   // [p][k] stride 68
  __shared__ alignas(16) float sS2[64 * 36];   // [p][j] stride 36
  __shared__ float sWc[32], sbb[32], sbc;
  const int t = threadIdx.x;
#pragma unroll
  for (int i = t * 4; i < 64 * 32; i += 1024) {
    int r = i >> 5, c = i & 31;
    *(float4*)&sWb[r * 36 + c] = *(const float4*)&Wb[i];
  }
  if (t < 32) { sWc[t] = Wc[t]; sbb[t] = bb[t]; }
  if (t == 0) sbc = bc[0];
  const int base = blockIdx.x << 6;
  {  // gather + add + relu -> s1
    int p = t >> 2, q = t & 3;
    int e = base + p; if (e >= ES) e = ES - 1;
    const float* r0 = U + (size_t)p0[e] * 128;        // U0 half: cols 0..63
    const float* r1 = U + (size_t)p1[e] * 128 + 64;   // U1 half: cols 64..127
#pragma unroll
    for (int i = 0; i < 4; i++) {
      int c = i * 16 + q * 4;
      float4 a = *(const float4*)&r0[c];
      float4 b = *(const float4*)&r1[c];
      float4 o;
      o.x = fmaxf(a.x + b.x, 0.f); o.y = fmaxf(a.y + b.y, 0.f);
      o.z = fmaxf(a.z + b.z, 0.f); o.w = fmaxf(a.w + b.w, 0.f);
      *(float4*)&sS1[p * 68 + c] = o;
    }
  }
  __syncthreads();
  // layer b: rows rg*4+ri, cols cg*2..+1
  const int rg = t >> 4, cg = t & 15;
  float accb[4][2] = {};
#pragma unroll
  for (int k0 = 0; k0 < 64; k0 += 4) {
    float4 av[4];
#pragma unroll
    for (int ri = 0; ri < 4; ri++) av[ri] = *(const float4*)&sS1[(rg * 4 + ri) * 68 + k0];
    float2 wv[4];
#pragma unroll
    for (int kk = 0; kk < 4; kk++) wv[kk] = *(const float2*)&sWb[(k0 + kk) * 36 + cg * 2];
#pragma unroll
    for (int kk = 0; kk < 4; kk++)
#pragma unroll
      for (int ri = 0; ri < 4; ri++) {
        float a = ((const float*)&av[ri])[kk];
        accb[ri][0] = fmaf(a, wv[kk].x, accb[ri][0]);
        accb[ri][1] = fmaf(a, wv[kk].y, accb[ri][1]);
      }
  }
#pragma unroll
  for (int ri = 0; ri < 4; ri++) {
    float2 o;
    o.x = fmaxf(accb[ri][0] + sbb[cg * 2 + 0], 0.f);
    o.y = fmaxf(accb[ri][1] + sbb[cg * 2 + 1], 0.f);
    *(float2*)&sS2[(rg * 4 + ri) * 36 + cg * 2] = o;
  }
  __syncthreads();
  {  // layer c
    int p = t >> 2, q = t & 3;
    float s = 0.f;
#pragma unroll
    for (int jj = 0; jj < 8; jj++) {
      int j = q + jj * 4;
      s = fmaf(sS2[p * 36 + j], sWc[j], s);
    }
    s += __shfl_down(s, 2);
    s += __shfl_down(s, 1);
    if (q == 0 && base + p < ES) logits[base + p] = s + sbc;
  }
}

// ---------- fused per-graph softmax: one block per graph (eg sorted) ----------
DEVINL int lbound(const int* __restrict__ a, int n, int key) {
  int lo = 0, hi = n;
  while (lo < hi) { int mid = (lo + hi) >> 1; if (a[mid] < key) lo = mid + 1; else hi = mid; }
  return lo;
}
__global__ void k_softmax(const float* __restrict__ logits, const int* __restrict__ eg,
                          float* __restrict__ out, int ES) {
  const int g = blockIdx.x;
  const int t = threadIdx.x;
  const int lo = lbound(eg, ES, g);
  const int hi = lbound(eg, ES, g + 1);
  if (lo >= hi) return;
  __shared__ float red[256];
  __shared__ float s_m, s_z;
  float m = -3.4e38f;
  for (int i = lo + t; i < hi; i += 256) m = fmaxf(m, logits[i]);
  red[t] = m; __syncthreads();
#pragma unroll
  for (int off = 128; off >= 1; off >>= 1) {
    if (t < off) red[t] = fmaxf(red[t], red[t + off]);
    __syncthreads();
  }
  if (t == 0) s_m = red[0];
  __syncthreads();
  const float gm = s_m;
  float z = 0.f;
  for (int i = lo + t; i < hi; i += 256) z += expf(logits[i] - gm);
  red[t] = z; __syncthreads();
#pragma unroll
  for (int off = 128; off >= 1; off >>= 1) {
    if (t < off) red[t] += red[t + off];
    __syncthreads();
  }
  if (t == 0) s_z = red[0];
  __syncthreads();
  const float inv = 1.0f / s_z;
  for (int i = lo + t; i < hi; i += 256) out[i] = expf(logits[i] - gm) * inv;
}

// ---------------------------------------------------------------------------
extern "C" void kernel_launch(void* const* d_in, const int* in_sizes, int n_in,
                              void* d_out, int out_size, void* d_ws, size_t ws_size,
                              hipStream_t stream) {
  const float* x  = (const float*)d_in[0];
  const int* ei   = (const int*)d_in[1];
  const float* ew = (const float*)d_in[2];
  const int* pi   = (const int*)d_in[3];
  const int* eg   = (const int*)d_in[4];
  const float* Wp = (const float*)d_in[6];
  const float* bp = (const float*)d_in[7];
  const float* W1 = (const float*)d_in[8];
  const float* b1 = (const float*)d_in[9];
  const float* W2 = (const float*)d_in[10];
  const float* b2 = (const float*)d_in[11];
  const float* Wa = (const float*)d_in[12];
  const float* ba = (const float*)d_in[13];
  const float* Wb = (const float*)d_in[14];
  const float* bb = (const float*)d_in[15];
  const float* Wc = (const float*)d_in[16];
  const float* bc = (const float*)d_in[17];

  const int N  = in_sizes[0] / 64;
  const int E  = in_sizes[2];
  const int ES = in_sizes[4];
  const int G  = 128;

  float* ws = (float*)d_ws;
  size_t o = 0;
  int* cnt = (int*)(ws + o);   o += ((size_t)N + 31) & ~(size_t)31;
  float* dinv = (float*)cnt;   // reuse after scan
  int* start = (int*)(ws + o); o += ((size_t)N + 31) & ~(size_t)31;
  int* bsum = (int*)(ws + o);  o += 512;
  int* boff = (int*)(ws + o);  o += 512;
  int2* pk = (int2*)(ws + o);  o += (size_t)E * 2;
  float* A = ws + o;           o += (size_t)N * 128;   // h1 -> U
  float* B = ws + o;           o += (size_t)N * 128;   // hw1 -> V -> logits
  float* Wfuse = ws + o;       o += 8192;
  float* bfuse = ws + o;       o += 128;
  float* Mcat = ws + o;        o += 16384;
  float* bU = ws + o;          o += 128;

  const int* row = ei;
  const int* col = ei + E;
  const int* p0 = pi;
  const int* p1 = pi + ES;
  float* out = (float*)d_out;

  const int gN = (N + 255) / 256;
  const int gE = (E + 255) / 256;
  const int nb = gN;

  // ---- weight folding + CSR build ----
  hipMemsetAsync(cnt, 0, (size_t)N * sizeof(int), stream);
  k_prep<<<98, 256, 0, stream>>>(Wp, bp, W1, W2, Wa, ba, b2, Wfuse, bfuse, Mcat, bU);
  k_hist<<<gE, 256, 0, stream>>>(col, cnt, E);
  k_scan1<<<nb, 256, 0, stream>>>(cnt, start, bsum, N);
  k_scan2<<<1, 512, 0, stream>>>(bsum, boff, nb);
  k_scan3<<<nb, 256, 0, stream>>>(start, boff, N);
  k_fill<<<gE, 256, 0, stream>>>(row, col, ew, start, pk, E);
  k_dinv_csr<<<gN, 256, 0, stream>>>(start, pk, dinv, N);
  k_permnorm<<<gE, 256, 0, stream>>>(pk, dinv, E);

  // ---- node pipeline: 2 GEMMs + 2 gathers ----
  const int gRows = (N + 127) / 128;
  k_gemm<64, 128, true><<<gRows, 256, 0, stream>>>(x, Wfuse, bfuse, B, N);   // hw1
  k_gather<128, true><<<(N + 7) / 8, 256, 0, stream>>>(start, pk, B, dinv, b1, A, N);   // h1
  k_gemm<128, 128, false><<<gRows, 256, 0, stream>>>(A, Mcat, nullptr, B, N); // V
  k_gather<128, false><<<(N + 7) / 8, 256, 0, stream>>>(start, pk, B, dinv, bU, A, N);  // U

  // ---- per-edge MLP ----
  const int nTiles = (ES + 63) / 64;
  k_edge<<<nTiles, 256, 0, stream>>>(A, p0, p1, Wb, bb, Wc, bc, B, ES);

  // ---- per-graph softmax ----
  k_softmax<<<G, 256, 0, stream>>>(B, eg, out, ES);
}